// Round 1
// baseline (2601.220 us; speedup 1.0000x reference)
//
#include <hip/hip_runtime.h>
#include <math.h>

#define T_SEQ   1024
#define BATCH   2
#define CDIM    1024
#define NHEAD   16
#define VHEAD   32
#define NOPE_D  32
#define ROPED   64
#define KEEP    256
#define HEAD_D  96   // NOPE + ROPE
#define SCALE_ATTN 0.1020620726159658f  // 1/sqrt(96)

// flash tile params
#define BQ   32     // queries per block
#define BKT  64     // keys per tile
#define SK   100    // Q/K LDS row stride (floats): 100%32=4 -> <=2-way on b128 (free)
#define SPV  36     // V LDS row stride: 36%32=4 -> <=2-way on b128 (free)

// ---------------------------------------------------------------------------
// Generic fp32 tiled GEMM: C[M,N] = A[M,K] @ B[K,N], row-major.
// ---------------------------------------------------------------------------
__global__ __launch_bounds__(256) void gemm_tiled(const float* __restrict__ A,
                                                  const float* __restrict__ B,
                                                  float* __restrict__ C,
                                                  int M, int N, int K) {
    __shared__ float As[16][65];
    __shared__ float Bs[16][64];
    int tid = threadIdx.x;
    int tx = tid & 15, ty = tid >> 4;
    int row0 = blockIdx.y * 64, col0 = blockIdx.x * 64;
    float acc[4][4] = {};
    for (int k0 = 0; k0 < K; k0 += 16) {
#pragma unroll
        for (int r = 0; r < 4; r++) {
            int idx = tid + 256 * r;
            int kk = idx & 15, m = idx >> 4;
            int gr = row0 + m, gc = k0 + kk;
            As[kk][m] = (gr < M && gc < K) ? A[(size_t)gr * K + gc] : 0.f;
        }
#pragma unroll
        for (int r = 0; r < 4; r++) {
            int idx = tid + 256 * r;
            int n = idx & 63, kk = idx >> 6;
            int gr = k0 + kk, gc = col0 + n;
            Bs[kk][n] = (gr < K && gc < N) ? B[(size_t)gr * N + gc] : 0.f;
        }
        __syncthreads();
#pragma unroll
        for (int kk = 0; kk < 16; kk++) {
            float a[4], b[4];
#pragma unroll
            for (int i = 0; i < 4; i++) a[i] = As[kk][ty + 16 * i];
#pragma unroll
            for (int j = 0; j < 4; j++) b[j] = Bs[kk][tx + 16 * j];
#pragma unroll
            for (int i = 0; i < 4; i++)
#pragma unroll
                for (int j = 0; j < 4; j++) acc[i][j] += a[i] * b[j];
        }
        __syncthreads();
    }
#pragma unroll
    for (int i = 0; i < 4; i++) {
        int gr = row0 + ty + 16 * i;
        if (gr >= M) continue;
#pragma unroll
        for (int j = 0; j < 4; j++) {
            int gc = col0 + tx + 16 * j;
            if (gc < N) C[(size_t)gr * N + gc] = acc[i][j];
        }
    }
}

// ---------------------------------------------------------------------------
__global__ void rms_rows(float* __restrict__ buf, const float* __restrict__ g, int D) {
    int row = blockIdx.x;
    int lane = threadIdx.x;  // blockDim = 64
    float ss = 0.f;
    for (int d = lane; d < D; d += 64) {
        float v = buf[(size_t)row * D + d];
        ss += v * v;
    }
    for (int off = 32; off; off >>= 1) ss += __shfl_xor(ss, off, 64);
    float r = rsqrtf(ss / (float)D + 1e-6f);
    for (int d = lane; d < D; d += 64) buf[(size_t)row * D + d] *= r * g[d];
}

// ---------------------------------------------------------------------------
__global__ void rope_inplace(float* __restrict__ buf, int nrows, int rstride,
                             int nheads, int hstride, int roff, int posmod,
                             float scale) {
    int total = nrows * nheads * 32;
    for (int it = blockIdx.x * blockDim.x + threadIdx.x; it < total;
         it += gridDim.x * blockDim.x) {
        int i = it & 31;
        int hr = it >> 5;
        int h = hr % nheads;
        int row = hr / nheads;
        int pos = row % posmod;
        float expo = (float)i * (1.0f / 32.0f);
        float f = 1.0f / powf(10000.0f, expo);
        float a = (float)pos * f;
        float s, c;
        sincosf(a, &s, &c);
        size_t base = (size_t)row * rstride + (size_t)h * hstride + roff;
        float v1 = buf[base + i], v2 = buf[base + 32 + i];
        buf[base + i]      = (v1 * c - v2 * s) * scale;
        buf[base + 32 + i] = (v1 * s + v2 * c) * scale;
    }
}

// ---------------------------------------------------------------------------
__global__ void scores_gate(const float* __restrict__ x,
                            const float* __restrict__ w_imp,
                            const float* __restrict__ w_gate,
                            float* __restrict__ scores,
                            float* __restrict__ gate_raw) {
    int wid = (blockIdx.x * blockDim.x + threadIdx.x) >> 6;
    int lane = threadIdx.x & 63;
    if (wid >= BATCH * T_SEQ) return;
    int b = wid >> 10;
    const float* xr = x + (size_t)wid * CDIM;
    float s0 = 0, g0 = 0, g1 = 0, g2 = 0;
    for (int c = lane; c < CDIM; c += 64) {
        float xv = xr[c];
        s0 += xv * w_imp[c];
        g0 += xv * w_gate[c * 3 + 0];
        g1 += xv * w_gate[c * 3 + 1];
        g2 += xv * w_gate[c * 3 + 2];
    }
    for (int off = 32; off; off >>= 1) {
        s0 += __shfl_xor(s0, off, 64);
        g0 += __shfl_xor(g0, off, 64);
        g1 += __shfl_xor(g1, off, 64);
        g2 += __shfl_xor(g2, off, 64);
    }
    if (lane == 0) {
        scores[wid] = s0;
        atomicAdd(&gate_raw[b * 3 + 0], g0);
        atomicAdd(&gate_raw[b * 3 + 1], g1);
        atomicAdd(&gate_raw[b * 3 + 2], g2);
    }
}

__global__ void gate_final(const float* __restrict__ gate_raw, float* __restrict__ gate) {
    int b = threadIdx.x;
    if (b >= BATCH) return;
    float v0 = gate_raw[b * 3 + 0] / (float)T_SEQ;
    float v1 = gate_raw[b * 3 + 1] / (float)T_SEQ;
    float v2 = gate_raw[b * 3 + 2] / (float)T_SEQ;
    float m = fmaxf(v0, fmaxf(v1, v2));
    float e0 = expf(v0 - m), e1 = expf(v1 - m), e2 = expf(v2 - m);
    float s = e0 + e1 + e2;
    gate[b * 3 + 0] = e0 / s;
    gate[b * 3 + 1] = e1 / s;
    gate[b * 3 + 2] = e2 / s;
}

// ---------------------------------------------------------------------------
__global__ void topk_kernel(const float* __restrict__ scores, int* __restrict__ idx) {
    int b = blockIdx.x;
    __shared__ float s[1024];
    __shared__ int ps[1024];
    int t = threadIdx.x;
    s[t] = scores[b * T_SEQ + t];
    __syncthreads();
    float mine = s[t];
    int rank = 0;
    for (int j = 0; j < 1024; j++) {
        float v = s[j];
        rank += (v > mine) || (v == mine && j < t);
    }
    int selv = (rank < KEEP) ? 1 : 0;
    ps[t] = selv;
    __syncthreads();
    for (int off = 1; off < 1024; off <<= 1) {
        int add = (t >= off) ? ps[t - off] : 0;
        __syncthreads();
        ps[t] += add;
        __syncthreads();
    }
    if (selv) idx[b * KEEP + ps[t] - 1] = t;
}

__global__ void gather_sel(const float* __restrict__ x, const int* __restrict__ idx,
                           float* __restrict__ sel) {
    for (size_t i = (size_t)blockIdx.x * blockDim.x + threadIdx.x;
         i < (size_t)BATCH * KEEP * CDIM; i += (size_t)gridDim.x * blockDim.x) {
        int c = (int)(i & (CDIM - 1));
        int r = (int)((i >> 10) & (KEEP - 1));
        int b = (int)(i >> 18);
        sel[i] = x[((size_t)b * T_SEQ + idx[b * KEEP + r]) * CDIM + c];
    }
}

// ---------------------------------------------------------------------------
// Fused 3-branch flash attention v3: register-resident online softmax.
// Mapping: thread t -> tq=t>>4 (q pair), tk=t&15 (k slice). The 16 threads of
// a tq-group are contiguous lanes of one wave -> row max/sum via __shfl_xor
// (offsets 1,2,4,8), no LDS, no barriers. PV: each thread accumulates partial
// O[2][32] over its own 4-key slice (rescaled by alpha per tile); a 4-step
// butterfly scatter-reduce (xor 8/4/2/1) folds the 16 partials at phase end,
// leaving each lane a float4-aligned slice of the output row.
// Only 2 __syncthreads per key tile (around K/V staging).
// Grid: (T/32, NHEAD, BATCH), 256 threads. LDS = 47.6 KB -> 3 blocks/CU.
// ---------------------------------------------------------------------------
__global__ __launch_bounds__(256) void flash_fused(
    const float* __restrict__ qn, const float* __restrict__ qr,
    const float* __restrict__ kn, const float* __restrict__ kr,
    const float* __restrict__ v1, const float* __restrict__ ksr,
    const float* __restrict__ vsr, const float* __restrict__ kwr,
    const float* __restrict__ vwr, const float* __restrict__ gate,
    float* __restrict__ out) {
    __shared__ float Qs[BQ * SK];    // 32 x 96 (stride 100)
    __shared__ float Ks[BKT * SK];   // 64 x 96 (stride 100)
    __shared__ float Vs[BKT * SPV];  // 64 x 32 (stride 36)

    int b = blockIdx.z, h = blockIdx.y;
    int q0 = blockIdx.x * BQ;
    int t = threadIdx.x;
    int tq = t >> 4, tk = t & 15;

    // stage Q tile (32 rows x 24 float4) — lives across all phases
    for (int i = t; i < BQ * 24; i += 256) {
        int row = i / 24, d4 = i % 24;
        size_t rq = (size_t)b * T_SEQ + q0 + row;
        float4 v;
        if (d4 < 8) v = *(const float4*)&qn[rq * 512 + h * 32 + d4 * 4];
        else        v = *(const float4*)&qr[rq * 1024 + h * 64 + (d4 - 8) * 4];
        *(float4*)&Qs[row * SK + d4 * 4] = v;
    }

    int qq0 = q0 + 2 * tq, qq1 = qq0 + 1;
    float comb[4] = {0.f, 0.f, 0.f, 0.f};

    for (int phase = 0; phase < 3; phase++) {
        bool causal = (phase != 1);
        int ntiles = causal ? ((q0 + BQ - 1) / BKT + 1) : (KEEP / BKT);

        float m0 = -1e30f, m1 = -1e30f, l0 = 0.f, l1 = 0.f;
        float o0[32], o1[32];
#pragma unroll
        for (int d = 0; d < 32; d++) { o0[d] = 0.f; o1[d] = 0.f; }

        for (int kt = 0; kt < ntiles; kt++) {
            int j0 = kt * BKT;
            __syncthreads();  // prev tile readers of Ks/Vs done (covers Qs staging 1st time)

            // stage K tile (64 rows x 24 float4)
            for (int i = t; i < BKT * 24; i += 256) {
                int row = i / 24, d4 = i % 24;
                int j = j0 + row;
                float4 v;
                if (phase == 0) {
                    size_t rk = (size_t)b * T_SEQ + j;
                    if (d4 < 8) v = *(const float4*)&kn[rk * 512 + h * 32 + d4 * 4];
                    else        v = *(const float4*)&kr[rk * 64 + (d4 - 8) * 4];
                } else if (phase == 1) {
                    v = *(const float4*)&ksr[((size_t)b * KEEP + j) * 1536 + h * 96 + d4 * 4];
                } else {
                    v = *(const float4*)&kwr[((size_t)b * T_SEQ + j) * 1536 + h * 96 + d4 * 4];
                }
                *(float4*)&Ks[row * SK + d4 * 4] = v;
            }
            // stage V tile (64 rows x 8 float4)
            for (int i = t; i < BKT * 8; i += 256) {
                int row = i >> 3, d4 = i & 7;
                int j = j0 + row;
                float4 v;
                if (phase == 0)      v = *(const float4*)&v1 [((size_t)b * T_SEQ + j) * 512 + h * 32 + d4 * 4];
                else if (phase == 1) v = *(const float4*)&vsr[((size_t)b * KEEP  + j) * 512 + h * 32 + d4 * 4];
                else                 v = *(const float4*)&vwr[((size_t)b * T_SEQ + j) * 512 + h * 32 + d4 * 4];
                *(float4*)&Vs[row * SPV + d4 * 4] = v;
            }
            __syncthreads();

            // S = Q.K^T  (2q x 4k per thread), registers only
            float s0[4] = {}, s1[4] = {};
#pragma unroll 6
            for (int d = 0; d < HEAD_D; d += 4) {
                float4 qa = *(float4*)&Qs[(2 * tq)     * SK + d];
                float4 qb = *(float4*)&Qs[(2 * tq + 1) * SK + d];
#pragma unroll
                for (int j = 0; j < 4; j++) {
                    float4 kv = *(float4*)&Ks[(16 * j + tk) * SK + d];
                    s0[j] += qa.x * kv.x + qa.y * kv.y + qa.z * kv.z + qa.w * kv.w;
                    s1[j] += qb.x * kv.x + qb.y * kv.y + qb.z * kv.z + qb.w * kv.w;
                }
            }
#pragma unroll
            for (int j = 0; j < 4; j++) {
                int kk = j0 + 16 * j + tk;
                s0[j] *= SCALE_ATTN;
                s1[j] *= SCALE_ATTN;
                if (causal && kk > qq0) s0[j] = -1e30f;
                if (causal && kk > qq1) s1[j] = -1e30f;
            }

            // row max via in-register reduce over the 16-lane tq group
            float mt0 = fmaxf(fmaxf(s0[0], s0[1]), fmaxf(s0[2], s0[3]));
            float mt1 = fmaxf(fmaxf(s1[0], s1[1]), fmaxf(s1[2], s1[3]));
#pragma unroll
            for (int off = 1; off <= 8; off <<= 1) {
                mt0 = fmaxf(mt0, __shfl_xor(mt0, off, 64));
                mt1 = fmaxf(mt1, __shfl_xor(mt1, off, 64));
            }
            float mn0 = fmaxf(m0, mt0), mn1 = fmaxf(m1, mt1);
            float a0 = __expf(m0 - mn0), a1 = __expf(m1 - mn1);
            m0 = mn0; m1 = mn1;

            float p0[4], p1[4];
            float rs0 = 0.f, rs1 = 0.f;
#pragma unroll
            for (int j = 0; j < 4; j++) {
                p0[j] = __expf(s0[j] - mn0); rs0 += p0[j];
                p1[j] = __expf(s1[j] - mn1); rs1 += p1[j];
            }
#pragma unroll
            for (int off = 1; off <= 8; off <<= 1) {
                rs0 += __shfl_xor(rs0, off, 64);
                rs1 += __shfl_xor(rs1, off, 64);
            }
            l0 = l0 * a0 + rs0;
            l1 = l1 * a1 + rs1;

            // rescale running partial O, then accumulate this tile's PV
#pragma unroll
            for (int d = 0; d < 32; d++) { o0[d] *= a0; o1[d] *= a1; }
#pragma unroll
            for (int j = 0; j < 4; j++) {
                int k = 16 * j + tk;
                float pj0 = p0[j], pj1 = p1[j];
#pragma unroll
                for (int d4 = 0; d4 < 8; d4++) {
                    float4 vv = *(float4*)&Vs[k * SPV + 4 * d4];
                    o0[4 * d4 + 0] += pj0 * vv.x; o0[4 * d4 + 1] += pj0 * vv.y;
                    o0[4 * d4 + 2] += pj0 * vv.z; o0[4 * d4 + 3] += pj0 * vv.w;
                    o1[4 * d4 + 0] += pj1 * vv.x; o1[4 * d4 + 1] += pj1 * vv.y;
                    o1[4 * d4 + 2] += pj1 * vv.z; o1[4 * d4 + 3] += pj1 * vv.w;
                }
            }
        }  // key tiles

        // butterfly scatter-reduce over the 16-lane tq group:
        // 64 partials -> each lane keeps the slice it will write.
        float r32[32];
        {
            bool hi = (tk & 8) != 0;
#pragma unroll
            for (int j = 0; j < 32; j++) {
                float snd = hi ? o0[j] : o1[j];               // pass what we don't keep
                float rcv = __shfl_xor(snd, 8, 64);
                r32[j] = (hi ? o1[j] : o0[j]) + rcv;
            }
        }
        float r16[16];
        {
            bool hi = (tk & 4) != 0;
#pragma unroll
            for (int j = 0; j < 16; j++) {
                float snd = hi ? r32[j] : r32[16 + j];
                float rcv = __shfl_xor(snd, 4, 64);
                r16[j] = (hi ? r32[16 + j] : r32[j]) + rcv;
            }
        }
        float r8[8];
        {
            bool hi = (tk & 2) != 0;
#pragma unroll
            for (int j = 0; j < 8; j++) {
                float snd = hi ? r16[j] : r16[8 + j];
                float rcv = __shfl_xor(snd, 2, 64);
                r8[j] = (hi ? r16[8 + j] : r16[j]) + rcv;
            }
        }
        float r4[4];
        {
            bool hi = (tk & 1) != 0;
#pragma unroll
            for (int j = 0; j < 4; j++) {
                float snd = hi ? r8[j] : r8[4 + j];
                float rcv = __shfl_xor(snd, 1, 64);
                r4[j] = (hi ? r8[4 + j] : r8[j]) + rcv;
            }
        }

        float g = gate[b * 3 + phase];
        float li = (tk & 8) ? l1 : l0;   // l is replicated across the group
        float inv = g / li;
#pragma unroll
        for (int c = 0; c < 4; c++) comb[c] += r4[c] * inv;
    }  // phases

    // lane tk owns row q0+2*tq+(tk>>3), cols (tk&7)*4 .. +3  (float4 aligned)
    size_t r0 = ((size_t)b * T_SEQ + q0 + 2 * tq + (tk >> 3)) * 512
              + h * 32 + (tk & 7) * 4;
    *(float4*)&out[r0] = make_float4(comb[0], comb[1], comb[2], comb[3]);
}

// ---------------------------------------------------------------------------
extern "C" void kernel_launch(void* const* d_in, const int* in_sizes, int n_in,
                              void* d_out, int out_size, void* d_ws, size_t ws_size,
                              hipStream_t stream) {
    const float* x        = (const float*)d_in[0];
    const float* w_cq     = (const float*)d_in[1];
    const float* g_qnorm  = (const float*)d_in[2];
    const float* w_dqn    = (const float*)d_in[3];
    const float* w_dqr    = (const float*)d_in[4];
    const float* w_ckv    = (const float*)d_in[5];
    const float* g_kvnorm = (const float*)d_in[6];
    const float* w_dkn    = (const float*)d_in[7];
    const float* w_dv     = (const float*)d_in[8];
    const float* w_krope  = (const float*)d_in[9];
    const float* w_imp    = (const float*)d_in[10];
    const float* w_selk   = (const float*)d_in[11];
    const float* w_selv   = (const float*)d_in[12];
    const float* w_wink   = (const float*)d_in[13];
    const float* w_winv   = (const float*)d_in[14];
    const float* w_gate   = (const float*)d_in[15];
    const float* w_proj   = (const float*)d_in[16];
    float* out = (float*)d_out;

    const int BT = BATCH * T_SEQ;  // 2048
    const int BS = BATCH * KEEP;   // 512

    float* ws = (float*)d_ws;
    size_t o = 0;
    float* nq     = ws + o; o += (size_t)BT * 96;
    float* ckv    = ws + o; o += (size_t)BT * 32;
    float* qn     = ws + o; o += (size_t)BT * 512;
    float* qr     = ws + o; o += (size_t)BT * 1024;
    float* knb    = ws + o; o += (size_t)BT * 512;
    float* vvb    = ws + o; o += (size_t)BT * 512;
    float* kro    = ws + o; o += (size_t)BT * 64;
    float* kwb    = ws + o; o += (size_t)BT * 1536;
    float* vwb    = ws + o; o += (size_t)BT * 512;
    float* ksb    = ws + o; o += (size_t)BS * 1536;
    float* vsb    = ws + o; o += (size_t)BS * 512;
    float* selb   = ws + o; o += (size_t)BS * CDIM;
    float* scores = ws + o; o += 2048;
    float* gateraw= ws + o; o += 8;
    float* gatef  = ws + o; o += 8;
    int*   idx    = (int*)(ws + o); o += 512;
    float* attn   = ws + o; o += (size_t)BT * 512;

    hipMemsetAsync(gateraw, 0, 8 * sizeof(float), stream);

    dim3 blk(256);
    auto gemm = [&](const float* A, const float* Bm, float* C, int M, int N, int K) {
        dim3 grid((N + 63) / 64, (M + 63) / 64);
        gemm_tiled<<<grid, blk, 0, stream>>>(A, Bm, C, M, N, K);
    };

    // Projections off x
    gemm(x, w_cq, nq, BT, 96, CDIM);
    rms_rows<<<BT, 64, 0, stream>>>(nq, g_qnorm, 96);
    gemm(nq, w_dqn, qn, BT, 512, 96);
    gemm(nq, w_dqr, qr, BT, 1024, 96);
    rope_inplace<<<2048, 256, 0, stream>>>(qr, BT, 1024, 16, 64, 0, T_SEQ, 1.0f);

    gemm(x, w_ckv, ckv, BT, 32, CDIM);
    rms_rows<<<BT, 64, 0, stream>>>(ckv, g_kvnorm, 32);
    gemm(ckv, w_dkn, knb, BT, 512, 32);
    gemm(ckv, w_dv, vvb, BT, 512, 32);

    gemm(x, w_krope, kro, BT, 64, CDIM);
    rope_inplace<<<256, 256, 0, stream>>>(kro, BT, 64, 1, 0, 0, T_SEQ, 1.0f / NHEAD);

    gemm(x, w_wink, kwb, BT, 1536, CDIM);
    rope_inplace<<<2048, 256, 0, stream>>>(kwb, BT, 1536, 16, 96, 32, T_SEQ, 1.0f);
    gemm(x, w_winv, vwb, BT, 512, CDIM);

    // scores + gate
    scores_gate<<<(BT * 64 + 255) / 256, 256, 0, stream>>>(x, w_imp, w_gate, scores, gateraw);
    gate_final<<<1, 64, 0, stream>>>(gateraw, gatef);

    // top-k select
    topk_kernel<<<BATCH, 1024, 0, stream>>>(scores, idx);
    gather_sel<<<2048, 256, 0, stream>>>(x, idx, selb);
    gemm(selb, w_selk, ksb, BS, 1536, CDIM);
    rope_inplace<<<512, 256, 0, stream>>>(ksb, BS, 1536, 16, 96, 32, KEEP, 1.0f);
    gemm(selb, w_selv, vsb, BS, 512, CDIM);

    // fused attention
    dim3 fgrid(T_SEQ / BQ, NHEAD, BATCH);
    flash_fused<<<fgrid, 256, 0, stream>>>(qn, qr, knb, kro, vvb, ksb, vsb, kwb,
                                           vwb, gatef, attn);

    // output projection
    gemm(attn, w_proj, out, BT, CDIM, 512);
}

// Round 2
// 2069.703 us; speedup vs baseline: 1.2568x; 1.2568x over previous
//
#include <hip/hip_runtime.h>
#include <math.h>

#define T_SEQ   1024
#define BATCH   2
#define CDIM    1024
#define NHEAD   16
#define VHEAD   32
#define NOPE_D  32
#define ROPED   64
#define KEEP    256
#define HEAD_D  96   // NOPE + ROPE
#define SCALE_ATTN 0.1020620726159658f  // 1/sqrt(96)

// flash tile params
#define BQ   32     // queries per block
#define BKT  64     // keys per tile
#define SK   100    // Q/K LDS row stride (floats): mult of 4, k*100%32=4k -> <=2-way on b128
#define SPT  34     // Pt row stride [k][q]: even -> aligned b64 column pairs
#define SPV  36     // V LDS row stride: mult of 4 for float4 staging, conflict-free b64 reads

// GEMM tile params
#define GBM 128
#define GBN 64
#define GBK 16
#define SA  132     // As row stride (pad): 132%32=4 -> 2-way max (free)

// ---------------------------------------------------------------------------
// fp32 tiled GEMM v2: C[M,N] = A[M,K] @ B[K,N], row-major.
// 128x64 block, 256 threads, 8x4 micro-tile, all-b128 LDS reads.
// Requires K%16==0 (all call sites satisfy), M/N guarded.
// ---------------------------------------------------------------------------
__global__ __launch_bounds__(256) void gemm_tiled(const float* __restrict__ A,
                                                  const float* __restrict__ B,
                                                  float* __restrict__ C,
                                                  int M, int N, int K) {
    __shared__ float As[GBK][SA];   // [k][m], transposed A tile
    __shared__ float Bs[GBK][GBN];  // [k][n]
    int t = threadIdx.x;
    int tx = t & 15;    // col group: cols tx*4 .. tx*4+3
    int ty = t >> 4;    // row group: rows ty*8 .. ty*8+7
    int row0 = blockIdx.y * GBM, col0 = blockIdx.x * GBN;
    float acc[8][4] = {};

    for (int k0 = 0; k0 < K; k0 += GBK) {
        // stage A: 128 rows x 16 k = 512 float4, 2 per thread, store transposed
#pragma unroll
        for (int r = 0; r < 2; r++) {
            int idx = t + 256 * r;           // 0..511
            int row = idx >> 2, k4 = idx & 3;
            int gr = row0 + row;
            float4 v = make_float4(0.f, 0.f, 0.f, 0.f);
            if (gr < M) v = *(const float4*)&A[(size_t)gr * K + k0 + k4 * 4];
            As[k4 * 4 + 0][row] = v.x;
            As[k4 * 4 + 1][row] = v.y;
            As[k4 * 4 + 2][row] = v.z;
            As[k4 * 4 + 3][row] = v.w;
        }
        // stage B: 16 k x 64 n = 256 float4, 1 per thread
        {
            int kk = t >> 4, n4 = t & 15;
            int gc = col0 + n4 * 4;
            float4 v = make_float4(0.f, 0.f, 0.f, 0.f);
            if (gc + 3 < N) {
                v = *(const float4*)&B[(size_t)(k0 + kk) * N + gc];
            } else if (gc < N) {
                const float* bp = &B[(size_t)(k0 + kk) * N];
                float tmp[4] = {0.f, 0.f, 0.f, 0.f};
                for (int j = 0; j < 4 && gc + j < N; j++) tmp[j] = bp[gc + j];
                v = make_float4(tmp[0], tmp[1], tmp[2], tmp[3]);
            }
            *(float4*)&Bs[kk][n4 * 4] = v;
        }
        __syncthreads();
#pragma unroll
        for (int kk = 0; kk < GBK; kk++) {
            float4 a0 = *(float4*)&As[kk][ty * 8];
            float4 a1 = *(float4*)&As[kk][ty * 8 + 4];
            float4 b0 = *(float4*)&Bs[kk][tx * 4];
            float av[8] = {a0.x, a0.y, a0.z, a0.w, a1.x, a1.y, a1.z, a1.w};
            float bv[4] = {b0.x, b0.y, b0.z, b0.w};
#pragma unroll
            for (int i = 0; i < 8; i++)
#pragma unroll
                for (int j = 0; j < 4; j++) acc[i][j] += av[i] * bv[j];
        }
        __syncthreads();
    }

#pragma unroll
    for (int i = 0; i < 8; i++) {
        int gr = row0 + ty * 8 + i;
        if (gr >= M) continue;
        int gc = col0 + tx * 4;
        if (gc + 3 < N) {
            *(float4*)&C[(size_t)gr * N + gc] =
                make_float4(acc[i][0], acc[i][1], acc[i][2], acc[i][3]);
        } else {
            for (int j = 0; j < 4 && gc + j < N; j++)
                C[(size_t)gr * N + gc + j] = acc[i][j];
        }
    }
}

// ---------------------------------------------------------------------------
__global__ void rms_rows(float* __restrict__ buf, const float* __restrict__ g, int D) {
    int row = blockIdx.x;
    int lane = threadIdx.x;  // blockDim = 64
    float ss = 0.f;
    for (int d = lane; d < D; d += 64) {
        float v = buf[(size_t)row * D + d];
        ss += v * v;
    }
    for (int off = 32; off; off >>= 1) ss += __shfl_xor(ss, off, 64);
    float r = rsqrtf(ss / (float)D + 1e-6f);
    for (int d = lane; d < D; d += 64) buf[(size_t)row * D + d] *= r * g[d];
}

// ---------------------------------------------------------------------------
__global__ void rope_inplace(float* __restrict__ buf, int nrows, int rstride,
                             int nheads, int hstride, int roff, int posmod,
                             float scale) {
    int total = nrows * nheads * 32;
    for (int it = blockIdx.x * blockDim.x + threadIdx.x; it < total;
         it += gridDim.x * blockDim.x) {
        int i = it & 31;
        int hr = it >> 5;
        int h = hr % nheads;
        int row = hr / nheads;
        int pos = row % posmod;
        float expo = (float)i * (1.0f / 32.0f);
        float f = 1.0f / powf(10000.0f, expo);
        float a = (float)pos * f;
        float s, c;
        sincosf(a, &s, &c);
        size_t base = (size_t)row * rstride + (size_t)h * hstride + roff;
        float v1 = buf[base + i], v2 = buf[base + 32 + i];
        buf[base + i]      = (v1 * c - v2 * s) * scale;
        buf[base + 32 + i] = (v1 * s + v2 * c) * scale;
    }
}

// ---------------------------------------------------------------------------
__global__ void scores_gate(const float* __restrict__ x,
                            const float* __restrict__ w_imp,
                            const float* __restrict__ w_gate,
                            float* __restrict__ scores,
                            float* __restrict__ gate_raw) {
    int wid = (blockIdx.x * blockDim.x + threadIdx.x) >> 6;
    int lane = threadIdx.x & 63;
    if (wid >= BATCH * T_SEQ) return;
    int b = wid >> 10;
    const float* xr = x + (size_t)wid * CDIM;
    float s0 = 0, g0 = 0, g1 = 0, g2 = 0;
    for (int c = lane; c < CDIM; c += 64) {
        float xv = xr[c];
        s0 += xv * w_imp[c];
        g0 += xv * w_gate[c * 3 + 0];
        g1 += xv * w_gate[c * 3 + 1];
        g2 += xv * w_gate[c * 3 + 2];
    }
    for (int off = 32; off; off >>= 1) {
        s0 += __shfl_xor(s0, off, 64);
        g0 += __shfl_xor(g0, off, 64);
        g1 += __shfl_xor(g1, off, 64);
        g2 += __shfl_xor(g2, off, 64);
    }
    if (lane == 0) {
        scores[wid] = s0;
        atomicAdd(&gate_raw[b * 3 + 0], g0);
        atomicAdd(&gate_raw[b * 3 + 1], g1);
        atomicAdd(&gate_raw[b * 3 + 2], g2);
    }
}

__global__ void gate_final(const float* __restrict__ gate_raw, float* __restrict__ gate) {
    int b = threadIdx.x;
    if (b >= BATCH) return;
    float v0 = gate_raw[b * 3 + 0] / (float)T_SEQ;
    float v1 = gate_raw[b * 3 + 1] / (float)T_SEQ;
    float v2 = gate_raw[b * 3 + 2] / (float)T_SEQ;
    float m = fmaxf(v0, fmaxf(v1, v2));
    float e0 = expf(v0 - m), e1 = expf(v1 - m), e2 = expf(v2 - m);
    float s = e0 + e1 + e2;
    gate[b * 3 + 0] = e0 / s;
    gate[b * 3 + 1] = e1 / s;
    gate[b * 3 + 2] = e2 / s;
}

// ---------------------------------------------------------------------------
__global__ void topk_kernel(const float* __restrict__ scores, int* __restrict__ idx) {
    int b = blockIdx.x;
    __shared__ float s[1024];
    __shared__ int ps[1024];
    int t = threadIdx.x;
    s[t] = scores[b * T_SEQ + t];
    __syncthreads();
    float mine = s[t];
    int rank = 0;
    for (int j = 0; j < 1024; j++) {
        float v = s[j];
        rank += (v > mine) || (v == mine && j < t);
    }
    int selv = (rank < KEEP) ? 1 : 0;
    ps[t] = selv;
    __syncthreads();
    for (int off = 1; off < 1024; off <<= 1) {
        int add = (t >= off) ? ps[t - off] : 0;
        __syncthreads();
        ps[t] += add;
        __syncthreads();
    }
    if (selv) idx[b * KEEP + ps[t] - 1] = t;
}

__global__ void gather_sel(const float* __restrict__ x, const int* __restrict__ idx,
                           float* __restrict__ sel) {
    for (size_t i = (size_t)blockIdx.x * blockDim.x + threadIdx.x;
         i < (size_t)BATCH * KEEP * CDIM; i += (size_t)gridDim.x * blockDim.x) {
        int c = (int)(i & (CDIM - 1));
        int r = (int)((i >> 10) & (KEEP - 1));
        int b = (int)(i >> 18);
        sel[i] = x[((size_t)b * T_SEQ + idx[b * KEEP + r]) * CDIM + c];
    }
}

// ---------------------------------------------------------------------------
// Fused 3-branch flash attention v2 (measured-best): 32-query x 64-key tiles,
// register micro-tiled S and PV, block-wide online softmax through LDS Pt[k][q].
// Grid: (T/32, NHEAD, BATCH), 256 threads.
// ---------------------------------------------------------------------------
__global__ __launch_bounds__(256) void flash_fused(
    const float* __restrict__ qn, const float* __restrict__ qr,
    const float* __restrict__ kn, const float* __restrict__ kr,
    const float* __restrict__ v1, const float* __restrict__ ksr,
    const float* __restrict__ vsr, const float* __restrict__ kwr,
    const float* __restrict__ vwr, const float* __restrict__ gate,
    float* __restrict__ out) {
    __shared__ float Qs[BQ * SK];    // 32 x 96 (stride 100)
    __shared__ float Ks[BKT * SK];   // 64 x 96 (stride 100)
    __shared__ float Vs[BKT * SPV];  // 64 x 32 (stride 36)
    __shared__ float Pt[BKT * SPT];  // [k][q] (stride 34)
    __shared__ float mrow[BQ], lrow[BQ], arow[BQ], mtil[BQ];

    int b = blockIdx.z, h = blockIdx.y;
    int q0 = blockIdx.x * BQ;
    int t = threadIdx.x;
    int tq = t >> 4, tk = t & 15;   // S mapping: q=2*tq+i, k=16*j+tk
    int qg = t >> 4, dg = t & 15;   // PV mapping: q=2*qg+i, d=2*dg+j

    // stage Q tile (32 rows x 24 float4)
    for (int i = t; i < BQ * 24; i += 256) {
        int row = i / 24, d4 = i % 24;
        size_t rq = (size_t)b * T_SEQ + q0 + row;
        float4 v;
        if (d4 < 8) v = *(const float4*)&qn[rq * 512 + h * 32 + d4 * 4];
        else        v = *(const float4*)&qr[rq * 1024 + h * 64 + (d4 - 8) * 4];
        *(float4*)&Qs[row * SK + d4 * 4] = v;
    }

    float comb[2][2] = {};
    for (int phase = 0; phase < 3; phase++) {
        bool causal = (phase != 1);
        int ntiles = causal ? ((q0 + BQ - 1) / BKT + 1) : (KEEP / BKT);
        float o00 = 0.f, o01 = 0.f, o10 = 0.f, o11 = 0.f;
        __syncthreads();   // previous phase readers of lrow done
        if (t < BQ) { mrow[t] = -1e30f; lrow[t] = 0.f; }

        for (int kt = 0; kt < ntiles; kt++) {
            int j0 = kt * BKT;
            __syncthreads();  // previous tile readers of Ks/Vs/Pt done (also covers Qs/mrow first time)

            // stage K tile (64 rows x 24 float4)
            for (int i = t; i < BKT * 24; i += 256) {
                int row = i / 24, d4 = i % 24;
                int j = j0 + row;
                float4 v;
                if (phase == 0) {
                    size_t rk = (size_t)b * T_SEQ + j;
                    if (d4 < 8) v = *(const float4*)&kn[rk * 512 + h * 32 + d4 * 4];
                    else        v = *(const float4*)&kr[rk * 64 + (d4 - 8) * 4];
                } else if (phase == 1) {
                    v = *(const float4*)&ksr[((size_t)b * KEEP + j) * 1536 + h * 96 + d4 * 4];
                } else {
                    v = *(const float4*)&kwr[((size_t)b * T_SEQ + j) * 1536 + h * 96 + d4 * 4];
                }
                *(float4*)&Ks[row * SK + d4 * 4] = v;
            }
            // stage V tile (64 rows x 8 float4)
            for (int i = t; i < BKT * 8; i += 256) {
                int row = i >> 3, d4 = i & 7;
                int j = j0 + row;
                float4 v;
                if (phase == 0)      v = *(const float4*)&v1 [((size_t)b * T_SEQ + j) * 512 + h * 32 + d4 * 4];
                else if (phase == 1) v = *(const float4*)&vsr[((size_t)b * KEEP  + j) * 512 + h * 32 + d4 * 4];
                else                 v = *(const float4*)&vwr[((size_t)b * T_SEQ + j) * 512 + h * 32 + d4 * 4];
                *(float4*)&Vs[row * SPV + d4 * 4] = v;
            }
            __syncthreads();

            // S = Q.K^T  (2q x 4k per thread)
            float s[2][4] = {};
#pragma unroll 6
            for (int d = 0; d < HEAD_D; d += 4) {
                float4 qa = *(float4*)&Qs[(2 * tq)     * SK + d];
                float4 qb = *(float4*)&Qs[(2 * tq + 1) * SK + d];
#pragma unroll
                for (int j = 0; j < 4; j++) {
                    float4 kv = *(float4*)&Ks[(16 * j + tk) * SK + d];
                    s[0][j] += qa.x * kv.x + qa.y * kv.y + qa.z * kv.z + qa.w * kv.w;
                    s[1][j] += qb.x * kv.x + qb.y * kv.y + qb.z * kv.z + qb.w * kv.w;
                }
            }
#pragma unroll
            for (int i = 0; i < 2; i++)
#pragma unroll
                for (int j = 0; j < 4; j++) {
                    int qq = q0 + 2 * tq + i;
                    int kk = j0 + 16 * j + tk;
                    float sv = s[i][j] * SCALE_ATTN;
                    if (causal && kk > qq) sv = -1e30f;
                    Pt[(16 * j + tk) * SPT + (2 * tq + i)] = sv;
                }
            __syncthreads();

            // tile row-max: q = t>>3, 8 lanes per row
            {
                int q = t >> 3, sub = t & 7;
                float mt = -1e30f;
#pragma unroll
                for (int i2 = 0; i2 < 8; i2++)
                    mt = fmaxf(mt, Pt[(sub * 8 + i2) * SPT + q]);
                mt = fmaxf(mt, __shfl_xor(mt, 1, 64));
                mt = fmaxf(mt, __shfl_xor(mt, 2, 64));
                mt = fmaxf(mt, __shfl_xor(mt, 4, 64));
                if (sub == 0) mtil[q] = mt;
            }
            __syncthreads();
            if (t < BQ) {
                float mnew = fmaxf(mrow[t], mtil[t]);
                arow[t] = __expf(mrow[t] - mnew);
                mrow[t] = mnew;
            }
            __syncthreads();
            // exponentiate + row sums
            {
                int q = t >> 3, sub = t & 7;
                float mnew = mrow[q];
                float psum = 0.f;
#pragma unroll
                for (int i2 = 0; i2 < 8; i2++) {
                    int kk = sub * 8 + i2;
                    float p = __expf(Pt[kk * SPT + q] - mnew);
                    Pt[kk * SPT + q] = p;
                    psum += p;
                }
                psum += __shfl_xor(psum, 1, 64);
                psum += __shfl_xor(psum, 2, 64);
                psum += __shfl_xor(psum, 4, 64);
                if (sub == 0) lrow[q] = lrow[q] * arow[q] + psum;
            }
            __syncthreads();

            // O accumulate (2q x 2d per thread)
            {
                float a0 = arow[2 * qg], a1 = arow[2 * qg + 1];
                o00 *= a0; o01 *= a0; o10 *= a1; o11 *= a1;
#pragma unroll 8
                for (int kk = 0; kk < BKT; kk++) {
                    float2 pv = *(float2*)&Pt[kk * SPT + 2 * qg];
                    float2 vv = *(float2*)&Vs[kk * SPV + 2 * dg];
                    o00 += pv.x * vv.x; o01 += pv.x * vv.y;
                    o10 += pv.y * vv.x; o11 += pv.y * vv.y;
                }
            }
        }  // key tiles

        // gate combine (lrow visible: synced after exp step of last tile)
        {
            float g = gate[b * 3 + phase];
            float i0 = g / lrow[2 * qg], i1 = g / lrow[2 * qg + 1];
            comb[0][0] += o00 * i0; comb[0][1] += o01 * i0;
            comb[1][0] += o10 * i1; comb[1][1] += o11 * i1;
        }
    }  // phases

    size_t r0 = ((size_t)b * T_SEQ + q0 + 2 * qg) * 512 + h * 32 + 2 * dg;
    out[r0]           = comb[0][0];
    out[r0 + 1]       = comb[0][1];
    out[r0 + 512]     = comb[1][0];
    out[r0 + 512 + 1] = comb[1][1];
}

// ---------------------------------------------------------------------------
extern "C" void kernel_launch(void* const* d_in, const int* in_sizes, int n_in,
                              void* d_out, int out_size, void* d_ws, size_t ws_size,
                              hipStream_t stream) {
    const float* x        = (const float*)d_in[0];
    const float* w_cq     = (const float*)d_in[1];
    const float* g_qnorm  = (const float*)d_in[2];
    const float* w_dqn    = (const float*)d_in[3];
    const float* w_dqr    = (const float*)d_in[4];
    const float* w_ckv    = (const float*)d_in[5];
    const float* g_kvnorm = (const float*)d_in[6];
    const float* w_dkn    = (const float*)d_in[7];
    const float* w_dv     = (const float*)d_in[8];
    const float* w_krope  = (const float*)d_in[9];
    const float* w_imp    = (const float*)d_in[10];
    const float* w_selk   = (const float*)d_in[11];
    const float* w_selv   = (const float*)d_in[12];
    const float* w_wink   = (const float*)d_in[13];
    const float* w_winv   = (const float*)d_in[14];
    const float* w_gate   = (const float*)d_in[15];
    const float* w_proj   = (const float*)d_in[16];
    float* out = (float*)d_out;

    const int BT = BATCH * T_SEQ;  // 2048
    const int BS = BATCH * KEEP;   // 512

    float* ws = (float*)d_ws;
    size_t o = 0;
    float* nq     = ws + o; o += (size_t)BT * 96;
    float* ckv    = ws + o; o += (size_t)BT * 32;
    float* qn     = ws + o; o += (size_t)BT * 512;
    float* qr     = ws + o; o += (size_t)BT * 1024;
    float* knb    = ws + o; o += (size_t)BT * 512;
    float* vvb    = ws + o; o += (size_t)BT * 512;
    float* kro    = ws + o; o += (size_t)BT * 64;
    float* kwb    = ws + o; o += (size_t)BT * 1536;
    float* vwb    = ws + o; o += (size_t)BT * 512;
    float* ksb    = ws + o; o += (size_t)BS * 1536;
    float* vsb    = ws + o; o += (size_t)BS * 512;
    float* selb   = ws + o; o += (size_t)BS * CDIM;
    float* scores = ws + o; o += 2048;
    float* gateraw= ws + o; o += 8;
    float* gatef  = ws + o; o += 8;
    int*   idx    = (int*)(ws + o); o += 512;
    float* attn   = ws + o; o += (size_t)BT * 512;

    hipMemsetAsync(gateraw, 0, 8 * sizeof(float), stream);

    dim3 blk(256);
    auto gemm = [&](const float* A, const float* Bm, float* C, int M, int N, int K) {
        dim3 grid((N + GBN - 1) / GBN, (M + GBM - 1) / GBM);
        gemm_tiled<<<grid, blk, 0, stream>>>(A, Bm, C, M, N, K);
    };

    // Projections off x
    gemm(x, w_cq, nq, BT, 96, CDIM);
    rms_rows<<<BT, 64, 0, stream>>>(nq, g_qnorm, 96);
    gemm(nq, w_dqn, qn, BT, 512, 96);
    gemm(nq, w_dqr, qr, BT, 1024, 96);
    rope_inplace<<<2048, 256, 0, stream>>>(qr, BT, 1024, 16, 64, 0, T_SEQ, 1.0f);

    gemm(x, w_ckv, ckv, BT, 32, CDIM);
    rms_rows<<<BT, 64, 0, stream>>>(ckv, g_kvnorm, 32);
    gemm(ckv, w_dkn, knb, BT, 512, 32);
    gemm(ckv, w_dv, vvb, BT, 512, 32);

    gemm(x, w_krope, kro, BT, 64, CDIM);
    rope_inplace<<<256, 256, 0, stream>>>(kro, BT, 64, 1, 0, 0, T_SEQ, 1.0f / NHEAD);

    gemm(x, w_wink, kwb, BT, 1536, CDIM);
    rope_inplace<<<2048, 256, 0, stream>>>(kwb, BT, 1536, 16, 96, 32, T_SEQ, 1.0f);
    gemm(x, w_winv, vwb, BT, 512, CDIM);

    // scores + gate
    scores_gate<<<(BT * 64 + 255) / 256, 256, 0, stream>>>(x, w_imp, w_gate, scores, gateraw);
    gate_final<<<1, 64, 0, stream>>>(gateraw, gatef);

    // top-k select
    topk_kernel<<<BATCH, 1024, 0, stream>>>(scores, idx);
    gather_sel<<<2048, 256, 0, stream>>>(x, idx, selb);
    gemm(selb, w_selk, ksb, BS, 1536, CDIM);
    rope_inplace<<<512, 256, 0, stream>>>(ksb, BS, 1536, 16, 96, 32, KEEP, 1.0f);
    gemm(selb, w_selv, vsb, BS, 512, CDIM);

    // fused attention
    dim3 fgrid(T_SEQ / BQ, NHEAD, BATCH);
    flash_fused<<<fgrid, 256, 0, stream>>>(qn, qr, knb, kro, vvb, ksb, vsb, kwb,
                                           vwb, gatef, attn);

    // output projection
    gemm(attn, w_proj, out, BT, CDIM, 512);
}

// Round 3
// 1496.486 us; speedup vs baseline: 1.7382x; 1.3830x over previous
//
#include <hip/hip_runtime.h>
#include <math.h>

#define T_SEQ   1024
#define BATCH   2
#define CDIM    1024
#define NHEAD   16
#define VHEAD   32
#define NOPE_D  32
#define ROPED   64
#define KEEP    256
#define HEAD_D  96   // NOPE + ROPE
#define SCALE_ATTN 0.1020620726159658f  // 1/sqrt(96)

// flash tile params
#define BQ   64     // queries per block (v3: doubled, 512 threads)
#define BKT  64     // keys per tile
#define SK   100    // Q/K LDS row stride (floats): mult of 4, k*100%32=4k -> <=2-way on b128
#define SPT  66     // Pt row stride [k][q]: even -> aligned b64 column pairs
#define SPV  36     // V LDS row stride: mult of 4 for float4 staging, conflict-free b64 reads

// GEMM tile params
#define GBM 128
#define GBN 64
#define GBK 16
#define SA  132     // As row stride (pad): 132%32=4 -> 2-way max (free)

// ---------------------------------------------------------------------------
// fp32 tiled GEMM v2: C[M,N] = A[M,K] @ B[K,N], row-major.
// 128x64 block, 256 threads, 8x4 micro-tile, all-b128 LDS reads.
// Requires K%16==0 (all call sites satisfy), M/N guarded.
// ---------------------------------------------------------------------------
__global__ __launch_bounds__(256) void gemm_tiled(const float* __restrict__ A,
                                                  const float* __restrict__ B,
                                                  float* __restrict__ C,
                                                  int M, int N, int K) {
    __shared__ float As[GBK][SA];   // [k][m], transposed A tile
    __shared__ float Bs[GBK][GBN];  // [k][n]
    int t = threadIdx.x;
    int tx = t & 15;    // col group: cols tx*4 .. tx*4+3
    int ty = t >> 4;    // row group: rows ty*8 .. ty*8+7
    int row0 = blockIdx.y * GBM, col0 = blockIdx.x * GBN;
    float acc[8][4] = {};

    for (int k0 = 0; k0 < K; k0 += GBK) {
        // stage A: 128 rows x 16 k = 512 float4, 2 per thread, store transposed
#pragma unroll
        for (int r = 0; r < 2; r++) {
            int idx = t + 256 * r;           // 0..511
            int row = idx >> 2, k4 = idx & 3;
            int gr = row0 + row;
            float4 v = make_float4(0.f, 0.f, 0.f, 0.f);
            if (gr < M) v = *(const float4*)&A[(size_t)gr * K + k0 + k4 * 4];
            As[k4 * 4 + 0][row] = v.x;
            As[k4 * 4 + 1][row] = v.y;
            As[k4 * 4 + 2][row] = v.z;
            As[k4 * 4 + 3][row] = v.w;
        }
        // stage B: 16 k x 64 n = 256 float4, 1 per thread
        {
            int kk = t >> 4, n4 = t & 15;
            int gc = col0 + n4 * 4;
            float4 v = make_float4(0.f, 0.f, 0.f, 0.f);
            if (gc + 3 < N) {
                v = *(const float4*)&B[(size_t)(k0 + kk) * N + gc];
            } else if (gc < N) {
                const float* bp = &B[(size_t)(k0 + kk) * N];
                float tmp[4] = {0.f, 0.f, 0.f, 0.f};
                for (int j = 0; j < 4 && gc + j < N; j++) tmp[j] = bp[gc + j];
                v = make_float4(tmp[0], tmp[1], tmp[2], tmp[3]);
            }
            *(float4*)&Bs[kk][n4 * 4] = v;
        }
        __syncthreads();
#pragma unroll
        for (int kk = 0; kk < GBK; kk++) {
            float4 a0 = *(float4*)&As[kk][ty * 8];
            float4 a1 = *(float4*)&As[kk][ty * 8 + 4];
            float4 b0 = *(float4*)&Bs[kk][tx * 4];
            float av[8] = {a0.x, a0.y, a0.z, a0.w, a1.x, a1.y, a1.z, a1.w};
            float bv[4] = {b0.x, b0.y, b0.z, b0.w};
#pragma unroll
            for (int i = 0; i < 8; i++)
#pragma unroll
                for (int j = 0; j < 4; j++) acc[i][j] += av[i] * bv[j];
        }
        __syncthreads();
    }

#pragma unroll
    for (int i = 0; i < 8; i++) {
        int gr = row0 + ty * 8 + i;
        if (gr >= M) continue;
        int gc = col0 + tx * 4;
        if (gc + 3 < N) {
            *(float4*)&C[(size_t)gr * N + gc] =
                make_float4(acc[i][0], acc[i][1], acc[i][2], acc[i][3]);
        } else {
            for (int j = 0; j < 4 && gc + j < N; j++)
                C[(size_t)gr * N + gc + j] = acc[i][j];
        }
    }
}

// ---------------------------------------------------------------------------
__global__ void rms_rows(float* __restrict__ buf, const float* __restrict__ g, int D) {
    int row = blockIdx.x;
    int lane = threadIdx.x;  // blockDim = 64
    float ss = 0.f;
    for (int d = lane; d < D; d += 64) {
        float v = buf[(size_t)row * D + d];
        ss += v * v;
    }
    for (int off = 32; off; off >>= 1) ss += __shfl_xor(ss, off, 64);
    float r = rsqrtf(ss / (float)D + 1e-6f);
    for (int d = lane; d < D; d += 64) buf[(size_t)row * D + d] *= r * g[d];
}

// ---------------------------------------------------------------------------
__global__ void rope_inplace(float* __restrict__ buf, int nrows, int rstride,
                             int nheads, int hstride, int roff, int posmod,
                             float scale) {
    int total = nrows * nheads * 32;
    for (int it = blockIdx.x * blockDim.x + threadIdx.x; it < total;
         it += gridDim.x * blockDim.x) {
        int i = it & 31;
        int hr = it >> 5;
        int h = hr % nheads;
        int row = hr / nheads;
        int pos = row % posmod;
        float expo = (float)i * (1.0f / 32.0f);
        float f = 1.0f / powf(10000.0f, expo);
        float a = (float)pos * f;
        float s, c;
        sincosf(a, &s, &c);
        size_t base = (size_t)row * rstride + (size_t)h * hstride + roff;
        float v1 = buf[base + i], v2 = buf[base + 32 + i];
        buf[base + i]      = (v1 * c - v2 * s) * scale;
        buf[base + 32 + i] = (v1 * s + v2 * c) * scale;
    }
}

// ---------------------------------------------------------------------------
__global__ void scores_gate(const float* __restrict__ x,
                            const float* __restrict__ w_imp,
                            const float* __restrict__ w_gate,
                            float* __restrict__ scores,
                            float* __restrict__ gate_raw) {
    int wid = (blockIdx.x * blockDim.x + threadIdx.x) >> 6;
    int lane = threadIdx.x & 63;
    if (wid >= BATCH * T_SEQ) return;
    int b = wid >> 10;
    const float* xr = x + (size_t)wid * CDIM;
    float s0 = 0, g0 = 0, g1 = 0, g2 = 0;
    for (int c = lane; c < CDIM; c += 64) {
        float xv = xr[c];
        s0 += xv * w_imp[c];
        g0 += xv * w_gate[c * 3 + 0];
        g1 += xv * w_gate[c * 3 + 1];
        g2 += xv * w_gate[c * 3 + 2];
    }
    for (int off = 32; off; off >>= 1) {
        s0 += __shfl_xor(s0, off, 64);
        g0 += __shfl_xor(g0, off, 64);
        g1 += __shfl_xor(g1, off, 64);
        g2 += __shfl_xor(g2, off, 64);
    }
    if (lane == 0) {
        scores[wid] = s0;
        atomicAdd(&gate_raw[b * 3 + 0], g0);
        atomicAdd(&gate_raw[b * 3 + 1], g1);
        atomicAdd(&gate_raw[b * 3 + 2], g2);
    }
}

__global__ void gate_final(const float* __restrict__ gate_raw, float* __restrict__ gate) {
    int b = threadIdx.x;
    if (b >= BATCH) return;
    float v0 = gate_raw[b * 3 + 0] / (float)T_SEQ;
    float v1 = gate_raw[b * 3 + 1] / (float)T_SEQ;
    float v2 = gate_raw[b * 3 + 2] / (float)T_SEQ;
    float m = fmaxf(v0, fmaxf(v1, v2));
    float e0 = expf(v0 - m), e1 = expf(v1 - m), e2 = expf(v2 - m);
    float s = e0 + e1 + e2;
    gate[b * 3 + 0] = e0 / s;
    gate[b * 3 + 1] = e1 / s;
    gate[b * 3 + 2] = e2 / s;
}

// ---------------------------------------------------------------------------
__global__ void topk_kernel(const float* __restrict__ scores, int* __restrict__ idx) {
    int b = blockIdx.x;
    __shared__ float s[1024];
    __shared__ int ps[1024];
    int t = threadIdx.x;
    s[t] = scores[b * T_SEQ + t];
    __syncthreads();
    float mine = s[t];
    int rank = 0;
    for (int j = 0; j < 1024; j++) {
        float v = s[j];
        rank += (v > mine) || (v == mine && j < t);
    }
    int selv = (rank < KEEP) ? 1 : 0;
    ps[t] = selv;
    __syncthreads();
    for (int off = 1; off < 1024; off <<= 1) {
        int add = (t >= off) ? ps[t - off] : 0;
        __syncthreads();
        ps[t] += add;
        __syncthreads();
    }
    if (selv) idx[b * KEEP + ps[t] - 1] = t;
}

__global__ void gather_sel(const float* __restrict__ x, const int* __restrict__ idx,
                           float* __restrict__ sel) {
    for (size_t i = (size_t)blockIdx.x * blockDim.x + threadIdx.x;
         i < (size_t)BATCH * KEEP * CDIM; i += (size_t)gridDim.x * blockDim.x) {
        int c = (int)(i & (CDIM - 1));
        int r = (int)((i >> 10) & (KEEP - 1));
        int b = (int)(i >> 18);
        sel[i] = x[((size_t)b * T_SEQ + idx[b * KEEP + r]) * CDIM + c];
    }
}

// ---------------------------------------------------------------------------
// Fused 3-branch flash attention v4: same 6-barrier online-softmax pipeline
// as measured-best v2, but BQ=64 with 512 threads:
//  - 16 waves/CU (was 8): 4 waves/SIMD latency hiding (VGPR capped 128)
//  - each K/V tile serves 64 queries: barrier events + K fetch per output halve
//  - z-flipped q-tile assignment balances causal cost across CU block pairs
// Grid: (T/64, NHEAD, BATCH), 512 threads. LDS = 78.3 KB -> 2 blocks/CU.
// ---------------------------------------------------------------------------
__global__ __launch_bounds__(512, 4) void flash_fused(
    const float* __restrict__ qn, const float* __restrict__ qr,
    const float* __restrict__ kn, const float* __restrict__ kr,
    const float* __restrict__ v1, const float* __restrict__ ksr,
    const float* __restrict__ vsr, const float* __restrict__ kwr,
    const float* __restrict__ vwr, const float* __restrict__ gate,
    float* __restrict__ out) {
    __shared__ float Qs[BQ * SK];    // 64 x 96 (stride 100)
    __shared__ float Ks[BKT * SK];   // 64 x 96 (stride 100)
    __shared__ float Vs[BKT * SPV];  // 64 x 32 (stride 36)
    __shared__ float Pt[BKT * SPT];  // [k][q] (stride 66)
    __shared__ float mrow[BQ], lrow[BQ], arow[BQ], mtil[BQ];

    int b = blockIdx.z, h = blockIdx.y;
    int qt = blockIdx.x;
    if (b == 1) qt = (gridDim.x - 1) - qt;   // balance causal cost across z-pairs
    int q0 = qt * BQ;
    int t = threadIdx.x;
    int tq = t >> 4, tk = t & 15;   // S mapping: q=2*tq+i (0..63), k=16*j+tk
    int qg = t >> 4, dg = t & 15;   // PV mapping: q=2*qg+i, d=2*dg+j

    // stage Q tile (64 rows x 24 float4)
    for (int i = t; i < BQ * 24; i += 512) {
        int row = i / 24, d4 = i % 24;
        size_t rq = (size_t)b * T_SEQ + q0 + row;
        float4 v;
        if (d4 < 8) v = *(const float4*)&qn[rq * 512 + h * 32 + d4 * 4];
        else        v = *(const float4*)&qr[rq * 1024 + h * 64 + (d4 - 8) * 4];
        *(float4*)&Qs[row * SK + d4 * 4] = v;
    }

    float comb[2][2] = {};
    for (int phase = 0; phase < 3; phase++) {
        bool causal = (phase != 1);
        int ntiles = causal ? (qt + 1) : (KEEP / BKT);
        float o00 = 0.f, o01 = 0.f, o10 = 0.f, o11 = 0.f;
        __syncthreads();   // previous phase readers of lrow done
        if (t < BQ) { mrow[t] = -1e30f; lrow[t] = 0.f; }

        for (int kt = 0; kt < ntiles; kt++) {
            int j0 = kt * BKT;
            __syncthreads();  // previous tile readers of Ks/Vs/Pt done (also covers Qs/mrow first time)

            // stage K tile (64 rows x 24 float4)
            for (int i = t; i < BKT * 24; i += 512) {
                int row = i / 24, d4 = i % 24;
                int j = j0 + row;
                float4 v;
                if (phase == 0) {
                    size_t rk = (size_t)b * T_SEQ + j;
                    if (d4 < 8) v = *(const float4*)&kn[rk * 512 + h * 32 + d4 * 4];
                    else        v = *(const float4*)&kr[rk * 64 + (d4 - 8) * 4];
                } else if (phase == 1) {
                    v = *(const float4*)&ksr[((size_t)b * KEEP + j) * 1536 + h * 96 + d4 * 4];
                } else {
                    v = *(const float4*)&kwr[((size_t)b * T_SEQ + j) * 1536 + h * 96 + d4 * 4];
                }
                *(float4*)&Ks[row * SK + d4 * 4] = v;
            }
            // stage V tile (64 rows x 8 float4)
            for (int i = t; i < BKT * 8; i += 512) {
                int row = i >> 3, d4 = i & 7;
                int j = j0 + row;
                float4 v;
                if (phase == 0)      v = *(const float4*)&v1 [((size_t)b * T_SEQ + j) * 512 + h * 32 + d4 * 4];
                else if (phase == 1) v = *(const float4*)&vsr[((size_t)b * KEEP  + j) * 512 + h * 32 + d4 * 4];
                else                 v = *(const float4*)&vwr[((size_t)b * T_SEQ + j) * 512 + h * 32 + d4 * 4];
                *(float4*)&Vs[row * SPV + d4 * 4] = v;
            }
            __syncthreads();

            // S = Q.K^T  (2q x 4k per thread)
            float s[2][4] = {};
#pragma unroll 6
            for (int d = 0; d < HEAD_D; d += 4) {
                float4 qa = *(float4*)&Qs[(2 * tq)     * SK + d];
                float4 qb = *(float4*)&Qs[(2 * tq + 1) * SK + d];
#pragma unroll
                for (int j = 0; j < 4; j++) {
                    float4 kv = *(float4*)&Ks[(16 * j + tk) * SK + d];
                    s[0][j] += qa.x * kv.x + qa.y * kv.y + qa.z * kv.z + qa.w * kv.w;
                    s[1][j] += qb.x * kv.x + qb.y * kv.y + qb.z * kv.z + qb.w * kv.w;
                }
            }
#pragma unroll
            for (int i = 0; i < 2; i++)
#pragma unroll
                for (int j = 0; j < 4; j++) {
                    int qq = q0 + 2 * tq + i;
                    int kk = j0 + 16 * j + tk;
                    float sv = s[i][j] * SCALE_ATTN;
                    if (causal && kk > qq) sv = -1e30f;
                    Pt[(16 * j + tk) * SPT + (2 * tq + i)] = sv;
                }
            __syncthreads();

            // tile row-max: q = t>>3, 8 lanes per row
            {
                int q = t >> 3, sub = t & 7;
                float mt = -1e30f;
#pragma unroll
                for (int i2 = 0; i2 < 8; i2++)
                    mt = fmaxf(mt, Pt[(sub * 8 + i2) * SPT + q]);
                mt = fmaxf(mt, __shfl_xor(mt, 1, 64));
                mt = fmaxf(mt, __shfl_xor(mt, 2, 64));
                mt = fmaxf(mt, __shfl_xor(mt, 4, 64));
                if (sub == 0) mtil[q] = mt;
            }
            __syncthreads();
            if (t < BQ) {
                float mnew = fmaxf(mrow[t], mtil[t]);
                arow[t] = __expf(mrow[t] - mnew);
                mrow[t] = mnew;
            }
            __syncthreads();
            // exponentiate + row sums
            {
                int q = t >> 3, sub = t & 7;
                float mnew = mrow[q];
                float psum = 0.f;
#pragma unroll
                for (int i2 = 0; i2 < 8; i2++) {
                    int kk = sub * 8 + i2;
                    float p = __expf(Pt[kk * SPT + q] - mnew);
                    Pt[kk * SPT + q] = p;
                    psum += p;
                }
                psum += __shfl_xor(psum, 1, 64);
                psum += __shfl_xor(psum, 2, 64);
                psum += __shfl_xor(psum, 4, 64);
                if (sub == 0) lrow[q] = lrow[q] * arow[q] + psum;
            }
            __syncthreads();

            // O accumulate (2q x 2d per thread)
            {
                float a0 = arow[2 * qg], a1 = arow[2 * qg + 1];
                o00 *= a0; o01 *= a0; o10 *= a1; o11 *= a1;
#pragma unroll 8
                for (int kk = 0; kk < BKT; kk++) {
                    float2 pv = *(float2*)&Pt[kk * SPT + 2 * qg];
                    float2 vv = *(float2*)&Vs[kk * SPV + 2 * dg];
                    o00 += pv.x * vv.x; o01 += pv.x * vv.y;
                    o10 += pv.y * vv.x; o11 += pv.y * vv.y;
                }
            }
        }  // key tiles

        // gate combine (lrow visible: synced after exp step of last tile)
        {
            float g = gate[b * 3 + phase];
            float i0 = g / lrow[2 * qg], i1 = g / lrow[2 * qg + 1];
            comb[0][0] += o00 * i0; comb[0][1] += o01 * i0;
            comb[1][0] += o10 * i1; comb[1][1] += o11 * i1;
        }
    }  // phases

    size_t r0 = ((size_t)b * T_SEQ + q0 + 2 * qg) * 512 + h * 32 + 2 * dg;
    out[r0]           = comb[0][0];
    out[r0 + 1]       = comb[0][1];
    out[r0 + 512]     = comb[1][0];
    out[r0 + 512 + 1] = comb[1][1];
}

// ---------------------------------------------------------------------------
extern "C" void kernel_launch(void* const* d_in, const int* in_sizes, int n_in,
                              void* d_out, int out_size, void* d_ws, size_t ws_size,
                              hipStream_t stream) {
    const float* x        = (const float*)d_in[0];
    const float* w_cq     = (const float*)d_in[1];
    const float* g_qnorm  = (const float*)d_in[2];
    const float* w_dqn    = (const float*)d_in[3];
    const float* w_dqr    = (const float*)d_in[4];
    const float* w_ckv    = (const float*)d_in[5];
    const float* g_kvnorm = (const float*)d_in[6];
    const float* w_dkn    = (const float*)d_in[7];
    const float* w_dv     = (const float*)d_in[8];
    const float* w_krope  = (const float*)d_in[9];
    const float* w_imp    = (const float*)d_in[10];
    const float* w_selk   = (const float*)d_in[11];
    const float* w_selv   = (const float*)d_in[12];
    const float* w_wink   = (const float*)d_in[13];
    const float* w_winv   = (const float*)d_in[14];
    const float* w_gate   = (const float*)d_in[15];
    const float* w_proj   = (const float*)d_in[16];
    float* out = (float*)d_out;

    const int BT = BATCH * T_SEQ;  // 2048
    const int BS = BATCH * KEEP;   // 512

    float* ws = (float*)d_ws;
    size_t o = 0;
    float* nq     = ws + o; o += (size_t)BT * 96;
    float* ckv    = ws + o; o += (size_t)BT * 32;
    float* qn     = ws + o; o += (size_t)BT * 512;
    float* qr     = ws + o; o += (size_t)BT * 1024;
    float* knb    = ws + o; o += (size_t)BT * 512;
    float* vvb    = ws + o; o += (size_t)BT * 512;
    float* kro    = ws + o; o += (size_t)BT * 64;
    float* kwb    = ws + o; o += (size_t)BT * 1536;
    float* vwb    = ws + o; o += (size_t)BT * 512;
    float* ksb    = ws + o; o += (size_t)BS * 1536;
    float* vsb    = ws + o; o += (size_t)BS * 512;
    float* selb   = ws + o; o += (size_t)BS * CDIM;
    float* scores = ws + o; o += 2048;
    float* gateraw= ws + o; o += 8;
    float* gatef  = ws + o; o += 8;
    int*   idx    = (int*)(ws + o); o += 512;
    float* attn   = ws + o; o += (size_t)BT * 512;

    hipMemsetAsync(gateraw, 0, 8 * sizeof(float), stream);

    dim3 blk(256);
    auto gemm = [&](const float* A, const float* Bm, float* C, int M, int N, int K) {
        dim3 grid((N + GBN - 1) / GBN, (M + GBM - 1) / GBM);
        gemm_tiled<<<grid, blk, 0, stream>>>(A, Bm, C, M, N, K);
    };

    // Projections off x
    gemm(x, w_cq, nq, BT, 96, CDIM);
    rms_rows<<<BT, 64, 0, stream>>>(nq, g_qnorm, 96);
    gemm(nq, w_dqn, qn, BT, 512, 96);
    gemm(nq, w_dqr, qr, BT, 1024, 96);
    rope_inplace<<<2048, 256, 0, stream>>>(qr, BT, 1024, 16, 64, 0, T_SEQ, 1.0f);

    gemm(x, w_ckv, ckv, BT, 32, CDIM);
    rms_rows<<<BT, 64, 0, stream>>>(ckv, g_kvnorm, 32);
    gemm(ckv, w_dkn, knb, BT, 512, 32);
    gemm(ckv, w_dv, vvb, BT, 512, 32);

    gemm(x, w_krope, kro, BT, 64, CDIM);
    rope_inplace<<<256, 256, 0, stream>>>(kro, BT, 64, 1, 0, 0, T_SEQ, 1.0f / NHEAD);

    gemm(x, w_wink, kwb, BT, 1536, CDIM);
    rope_inplace<<<2048, 256, 0, stream>>>(kwb, BT, 1536, 16, 96, 32, T_SEQ, 1.0f);
    gemm(x, w_winv, vwb, BT, 512, CDIM);

    // scores + gate
    scores_gate<<<(BT * 64 + 255) / 256, 256, 0, stream>>>(x, w_imp, w_gate, scores, gateraw);
    gate_final<<<1, 64, 0, stream>>>(gateraw, gatef);

    // top-k select
    topk_kernel<<<BATCH, 1024, 0, stream>>>(scores, idx);
    gather_sel<<<2048, 256, 0, stream>>>(x, idx, selb);
    gemm(selb, w_selk, ksb, BS, 1536, CDIM);
    rope_inplace<<<512, 256, 0, stream>>>(ksb, BS, 1536, 16, 96, 32, KEEP, 1.0f);
    gemm(selb, w_selv, vsb, BS, 512, CDIM);

    // fused attention
    dim3 fgrid(T_SEQ / BQ, NHEAD, BATCH);
    flash_fused<<<fgrid, 512, 0, stream>>>(qn, qr, knb, kro, vvb, ksb, vsb, kwb,
                                           vwb, gatef, attn);

    // output projection
    gemm(attn, w_proj, out, BT, CDIM, 512);
}